// Round 13
// baseline (242.319 us; speedup 1.0000x reference)
//
#include <hip/hip_runtime.h>
#include <hip/hip_cooperative_groups.h>

namespace cg = cooperative_groups;

#define NCLS 10

typedef _Float16 half8 __attribute__((ext_vector_type(8)));
typedef _Float16 h2 __attribute__((ext_vector_type(2)));
typedef __fp16 fp16x2 __attribute__((ext_vector_type(2)));
typedef float f32x4 __attribute__((ext_vector_type(4)));
typedef unsigned int u32;

#define MFMA(A, B, C) __builtin_amdgcn_mfma_f32_16x16x32_f16(A, B, C, 0, 0, 0)

union U4H8 { uint4 u; half8 h; h2 p[4]; u32 w[4]; };
union U2H4 { uint2 u; h2 p[2]; };
union HCVT { fp16x2 f; h2 h; u32 w; };

// node rows = 9 uint4 (8 data + 1 pad): linear addressing at ~4-way max alias
__device__ __forceinline__ int ri(int row, int c) { return row * 9 + c; }
__device__ __forceinline__ h2 pk2(float a, float b) { HCVT u; u.f = __builtin_amdgcn_cvt_pkrtz(a, b); return u.h; }
__device__ __forceinline__ u32 packh2(float a, float b) { HCVT u; u.f = __builtin_amdgcn_cvt_pkrtz(a, b); return u.w; }
__device__ __forceinline__ float fdot2f(h2 a, h2 b, float c) { return __builtin_amdgcn_fdot2(a, b, c, false); }
__device__ __forceinline__ float rsqf(float x) {
#if __has_builtin(__builtin_amdgcn_rsqf)
    return __builtin_amdgcn_rsqf(x);
#else
    return __builtin_amdgcn_rcpf(__builtin_amdgcn_sqrtf(x));
#endif
}
__device__ __forceinline__ float wave_sum(float v) {
#pragma unroll
    for (int m = 1; m < 64; m <<= 1) v += __shfl_xor(v, m, 64);
    return v;
}
__device__ __forceinline__ float red4(float v) {
    v += __shfl_xor(v, 16, 64);
    v += __shfl_xor(v, 32, 64);
    return v;
}

template <int N, bool EXACT>
__device__ __forceinline__ void combine_core(const U4H8 (&La)[N][2], const U4H8 (&Ra)[N][2],
                                             const U2H4 (&rv)[N][4], const half8 (&wfd)[2][4],
                                             U4H8 (&q)[N][2]) {
    float sd[N], lr[N], ll[N], rr[N];
#pragma unroll
    for (int n = 0; n < N; ++n) { sd[n] = 0.f; lr[n] = 0.f; ll[n] = 0.f; rr[n] = 0.f; }
#pragma unroll
    for (int mb = 0; mb < 4; ++mb)
#pragma unroll
        for (int n = 0; n < N; ++n) {
            f32x4 t = {0.f, 0.f, 0.f, 0.f};
#pragma unroll
            for (int kb = 0; kb < 2; ++kb) t = MFMA(wfd[kb][mb], La[n][kb].h, t);
            sd[n] = fdot2f(pk2(t[0], t[1]), rv[n][mb].p[0],
                           fdot2f(pk2(t[2], t[3]), rv[n][mb].p[1], sd[n]));
        }
#pragma unroll
    for (int n = 0; n < N; ++n)
#pragma unroll
        for (int kb = 0; kb < 2; ++kb)
#pragma unroll
            for (int i = 0; i < 4; ++i) {
                h2 l2 = La[n][kb].p[i], r2 = Ra[n][kb].p[i];
                lr[n] = fdot2f(l2, r2, lr[n]);
                if (EXACT) { ll[n] = fdot2f(l2, l2, ll[n]); rr[n] = fdot2f(r2, r2, rr[n]); }
            }
#pragma unroll
    for (int n = 0; n < N; ++n) {
        sd[n] = red4(sd[n]); lr[n] = red4(lr[n]);
        if (EXACT) { ll[n] = red4(ll[n]); rr[n] = red4(rr[n]); }
    }
#pragma unroll
    for (int n = 0; n < N; ++n) {
        float u = __expf(sd[n]);
        float a0 = __builtin_amdgcn_rcpf(1.f + u), a1 = 1.f - a0;
        float ms = EXACT ? (a0 * a0 * ll[n] + 2.f * a0 * a1 * lr[n] + a1 * a1 * rr[n]) * (1.f / 64.f)
                         : a0 * a0 + a1 * a1 + a0 * a1 * lr[n] * (2.f / 64.f);
        float sc = rsqf(ms + 1e-6f);
        h2 c0 = pk2(a0 * sc, a0 * sc), c1 = pk2(a1 * sc, a1 * sc);
#pragma unroll
        for (int kb = 0; kb < 2; ++kb)
#pragma unroll
            for (int i = 0; i < 4; ++i)
                q[n][kb].p[i] = c0 * La[n][kb].p[i] + c1 * Ra[n][kb].p[i];
    }
}

__device__ __forceinline__ void load_bfrag(const uint4* src, int row, int g, U4H8 (&A)[2]) {
    A[0].u = src[ri(row, g)];
    A[1].u = src[ri(row, g + 4)];
}
__device__ __forceinline__ void load_rv4(const uint4* src, int row, int g, U2H4 (&rv)[4]) {
    const uint2* s2 = (const uint2*)src;
#pragma unroll
    for (int mb = 0; mb < 4; ++mb) rv[mb].u = s2[ri(row, 2 * mb + (g >> 1)) * 2 + (g & 1)];
}
template <int N, bool EXACT>
__device__ __forceinline__ void combine_lds(const uint4* src, const int (&rowL)[N],
                                            const int (&rowR)[N], const half8 (&wfd)[2][4],
                                            int pl, int g, U4H8 (&q)[N][2]) {
    U4H8 La[N][2], Ra[N][2];
    U2H4 rv[N][4];
#pragma unroll
    for (int n = 0; n < N; ++n) {
        load_bfrag(src, rowL[n], g, La[n]);
        load_bfrag(src, rowR[n], g, Ra[n]);
        load_rv4(src, rowR[n], g, rv[n]);
    }
    combine_core<N, EXACT>(La, Ra, rv, wfd, q);
}

// ws layout (uint4): [0..511] Wd frags; [512..607] ermsh rows 0-11 (row 11 = RAW inf);
// batch b lev3 nodes at 1024+(b*128+r)*8 (LINEAR 8-chunk rows).
__device__ __forceinline__ void load_wfd(const uint4* ws4, half8 (&wfd)[2][4], int lane) {
#pragma unroll
    for (int fm = 0; fm < 8; ++fm) {
        U4H8 t;
        t.u = ws4[fm * 64 + lane];
        wfd[fm >> 2][fm & 3] = t.h;
    }
}

// ======================= kernel 0: setup =======================
__global__ void setup_kernel(const float* __restrict__ emb,
                             const float* __restrict__ rule_w, uint4* __restrict__ ws4) {
    int tid = threadIdx.x;
    int idx = blockIdx.x * 256 + tid;  // 0..2047
    {
        int e2 = idx & 3, lane = (idx >> 2) & 63, fm = idx >> 8;
        int kb = fm >> 2, mb = fm & 3, pl = lane & 15, g = lane >> 4;
        int i0 = 32 * kb + 8 * g + 2 * e2, j = 16 * mb + pl;
        float d0 = rule_w[4096 + i0 * 64 + j] - rule_w[i0 * 64 + j];
        float d1 = rule_w[4096 + (i0 + 1) * 64 + j] - rule_w[(i0 + 1) * 64 + j];
        ((u32*)ws4)[idx] = packh2(d0, d1);
    }
    if (blockIdx.x == 0 && tid < 64) {
        int lane = tid;
        u32* eg = (u32*)(ws4 + 512);
        for (int r = 0; r < 11; ++r) {
            float e = emb[r * 64 + lane];
            float ms = wave_sum(e * e) * (1.f / 64.f);
            float v = e * __builtin_amdgcn_rcpf(__builtin_amdgcn_sqrtf(ms + 1e-6f) + 1e-6f);
            u32 w = packh2(v, __shfl_xor(v, 1, 64));
            if ((lane & 1) == 0) eg[r * 32 + (lane >> 1)] = w;
        }
        float e = emb[640 + lane];  // raw inf token -> row 11
        u32 w = packh2(e, __shfl_xor(e, 1, 64));
        if ((lane & 1) == 0) eg[11 * 32 + (lane >> 1)] = w;
    }
}

// ============== cooperative fused kernel: fold -> grid.sync -> walk ==============
// smem rows: wave scratch 0-63 / 64-127 during fold; walker: tree 0-63,
// sv 64-107, res 109/110, A-ride 111-118, ermsh 128-139 (139 = raw inf).
__global__ void __launch_bounds__(128, 4) fused_kernel(
    const int* __restrict__ x, const int* __restrict__ qlo_p,
    const int* __restrict__ qhi_p, const float* __restrict__ lin_w,
    float* __restrict__ out, uint4* __restrict__ ws4) {
    __shared__ uint4 smem[140 * 9];  // 20.2 KB
    const int tid = threadIdx.x;
    const int lane = tid & 63, wave = tid >> 6;
    const int pl = lane & 15, g = lane >> 4;

    half8 wfd[2][4];
    load_wfd(ws4, wfd, lane);
    if (tid < 96) smem[ri(128 + (tid >> 3), tid & 7)] = ws4[512 + tid];
    __syncthreads();

    // ---- fold: grid-stride over 2048 units; each unit = 2 waves x 2 subtrees ----
    uint4* wtr = &smem[wave * 64 * 9];
    const int2* x2 = (const int2*)x;
    for (int unit = blockIdx.x; unit < 2048; unit += gridDim.x) {
        const int fb = unit >> 1;
#pragma unroll 1
        for (int ss = 0; ss < 2; ++ss) {
            const int s = (unit & 1) * 4 + wave * 2 + ss;
            int2 c00 = x2[fb * 512 + s * 64 + pl];
            int2 c01 = x2[fb * 512 + s * 64 + 16 + pl];
            int2 c10 = x2[fb * 512 + s * 64 + 32 + pl];
            int2 c11 = x2[fb * 512 + s * 64 + 48 + pl];
            U4H8 q[2][2];
            {
                int rL[2] = {128 + c00.x, 128 + c01.x}, rR[2] = {128 + c00.y, 128 + c01.y};
                combine_lds<2, false>(smem, rL, rR, wfd, pl, g, q);
                wtr[ri(pl, g)] = q[0][0].u;      wtr[ri(pl, g + 4)] = q[0][1].u;
                wtr[ri(16 + pl, g)] = q[1][0].u; wtr[ri(16 + pl, g + 4)] = q[1][1].u;
            }
            {
                int rL[2] = {128 + c10.x, 128 + c11.x}, rR[2] = {128 + c10.y, 128 + c11.y};
                combine_lds<2, false>(smem, rL, rR, wfd, pl, g, q);
                wtr[ri(32 + pl, g)] = q[0][0].u; wtr[ri(32 + pl, g + 4)] = q[0][1].u;
                wtr[ri(48 + pl, g)] = q[1][0].u; wtr[ri(48 + pl, g + 4)] = q[1][1].u;
            }
            asm volatile("s_waitcnt lgkmcnt(0)" ::: "memory");
            {
                int rL[2] = {2 * pl, 32 + 2 * pl}, rR[2] = {2 * pl + 1, 33 + 2 * pl};
                combine_lds<2, false>(wtr, rL, rR, wfd, pl, g, q);
                wtr[ri(pl, g)] = q[0][0].u;      wtr[ri(pl, g + 4)] = q[0][1].u;
                wtr[ri(16 + pl, g)] = q[1][0].u; wtr[ri(16 + pl, g + 4)] = q[1][1].u;
            }
            asm volatile("s_waitcnt lgkmcnt(0)" ::: "memory");
            {
                int rL[1] = {2 * pl}, rR[1] = {2 * pl + 1};
                U4H8 q1[1][2];
                combine_lds<1, false>(wtr, rL, rR, wfd, pl, g, q1);
                long gr = 1024 + (long)(fb * 128 + s * 16 + pl) * 8;
                ws4[gr + g] = q1[0][0].u;
                ws4[gr + 4 + g] = q1[0][1].u;
            }
            asm volatile("s_waitcnt lgkmcnt(0)" ::: "memory");
        }
    }
    __threadfence();
    cg::this_grid().sync();

    // ---- walk phase (wave 0, blocks grid-stride over 1024 batches) ----
    if (wave != 0) return;
    for (int b = blockIdx.x; b < 1024; b += gridDim.x) {
        const int lo = qlo_p[b], hi = qhi_p[b];
        const uint4* gb = ws4 + 1024 + (long)b * 1024;  // lev3 rows, LINEAR
        if (lane < 32) {
            int slot = lane >> 3, c = lane & 7;
            int il3 = lo >> 3, ih3 = hi >> 3;
            int t3 = (slot == 0) ? il3 : (slot == 1) ? (il3 ^ 1) : (slot == 2) ? ih3 : (ih3 ^ 1);
            smem[ri(76 + slot, c)] = gb[t3 * 8 + c];
            int t0 = (slot == 0) ? lo : (slot == 1) ? (lo ^ 1) : (slot == 2) ? hi : (hi ^ 1);
            int cls = x[b * 1024 + t0];
            smem[ri(64 + slot, c)] = smem[ri(128 + cls, c)];
        }
        asm volatile("s_waitcnt lgkmcnt(0) vmcnt(0)" ::: "memory");

        auto capl = [&](int lev, int node, const U4H8 (&qq)[2]) {
            int il = lo >> lev, ih = hi >> lev, cnt2 = 1024 >> lev;
            int svb = 64 + lev * 4;
            if (node == il) { smem[ri(svb, g)] = qq[0].u; smem[ri(svb, g + 4)] = qq[1].u; }
            if (((il ^ 1) < cnt2) && node == (il ^ 1)) { smem[ri(svb + 1, g)] = qq[0].u; smem[ri(svb + 1, g + 4)] = qq[1].u; }
            if (node == ih) { smem[ri(svb + 2, g)] = qq[0].u; smem[ri(svb + 2, g + 4)] = qq[1].u; }
            if (((ih ^ 1) < cnt2) && node == (ih ^ 1)) { smem[ri(svb + 3, g)] = qq[0].u; smem[ri(svb + 3, g + 4)] = qq[1].u; }
        };
        auto gfrag = [&](int row, U4H8 (&A)[2]) {
            A[0].u = gb[row * 8 + g];
            A[1].u = gb[row * 8 + 4 + g];
        };
        auto grv = [&](int row, U2H4 (&rv)[4]) {
            const uint2* g2 = (const uint2*)(gb + row * 8);
#pragma unroll
            for (int mb = 0; mb < 4; ++mb) rv[mb].u = g2[(2 * mb + (g >> 1)) * 2 + (g & 1)];
        };

        // lev4 from global operands -> smem rows 0-63
        {
            U4H8 La[2][2], Ra[2][2], qq[2][2];
            U2H4 rv[2][4];
            gfrag(2 * pl, La[0]); gfrag(2 * pl + 1, Ra[0]); grv(2 * pl + 1, rv[0]);
            gfrag(2 * (16 + pl), La[1]); gfrag(2 * (16 + pl) + 1, Ra[1]); grv(2 * (16 + pl) + 1, rv[1]);
            combine_core<2, false>(La, Ra, rv, wfd, qq);
            smem[ri(pl, g)] = qq[0][0].u;      smem[ri(pl, g + 4)] = qq[0][1].u;
            smem[ri(16 + pl, g)] = qq[1][0].u; smem[ri(16 + pl, g + 4)] = qq[1][1].u;
            capl(4, pl, qq[0]); capl(4, 16 + pl, qq[1]);
            gfrag(2 * (32 + pl), La[0]); gfrag(2 * (32 + pl) + 1, Ra[0]); grv(2 * (32 + pl) + 1, rv[0]);
            gfrag(2 * (48 + pl), La[1]); gfrag(2 * (48 + pl) + 1, Ra[1]); grv(2 * (48 + pl) + 1, rv[1]);
            combine_core<2, false>(La, Ra, rv, wfd, qq);
            smem[ri(32 + pl, g)] = qq[0][0].u; smem[ri(32 + pl, g + 4)] = qq[0][1].u;
            smem[ri(48 + pl, g)] = qq[1][0].u; smem[ri(48 + pl, g + 4)] = qq[1][1].u;
            capl(4, 32 + pl, qq[0]); capl(4, 48 + pl, qq[1]);
        }
        asm volatile("s_waitcnt lgkmcnt(0)" ::: "memory");
        U4H8 q[2][2];
        // lev5
        {
            int rL[2] = {2 * pl, 32 + 2 * pl}, rR[2] = {2 * pl + 1, 33 + 2 * pl};
            combine_lds<2, false>(smem, rL, rR, wfd, pl, g, q);
            smem[ri(pl, g)] = q[0][0].u;      smem[ri(pl, g + 4)] = q[0][1].u;
            smem[ri(16 + pl, g)] = q[1][0].u; smem[ri(16 + pl, g + 4)] = q[1][1].u;
            capl(5, pl, q[0]); capl(5, 16 + pl, q[1]);
        }
        asm volatile("s_waitcnt lgkmcnt(0)" ::: "memory");
        // lev6 + A-ride (8 lev1 sv-support nodes from leaves)
        const int il1 = lo >> 1, ih1 = hi >> 1, il2 = lo >> 2, ih2 = hi >> 2;
        {
            bool aact = pl < 8;
            int nn1 = 0;
            if (aact) {
                int base2 = (pl < 4) ? ((pl < 2) ? il2 : (il2 ^ 1))
                                     : ((pl < 6) ? ih2 : (ih2 ^ 1));
                nn1 = 2 * base2 + (pl & 1);
            }
            int2 lv = aact ? x2[b * 512 + nn1] : make_int2(0, 0);
            int rL[2] = {2 * pl, aact ? 128 + lv.x : 128};
            int rR[2] = {2 * pl + 1, aact ? 128 + lv.y : 128};
            combine_lds<2, false>(smem, rL, rR, wfd, pl, g, q);
            asm volatile("s_waitcnt lgkmcnt(0)" ::: "memory");
            smem[ri(pl, g)] = q[0][0].u; smem[ri(pl, g + 4)] = q[0][1].u;
            capl(6, pl, q[0]);
            if (aact) { smem[ri(111 + pl, g)] = q[1][0].u; smem[ri(111 + pl, g + 4)] = q[1][1].u; }
        }
        asm volatile("s_waitcnt lgkmcnt(0)" ::: "memory");
        if (lane < 32) {
            int slot = lane >> 3, c = lane & 7;
            int srcrow = (slot == 0) ? 111 + (il1 & 1)
                       : (slot == 1) ? 111 + ((il1 & 1) ^ 1)
                       : (slot == 2) ? 115 + (ih1 & 1)
                                     : 115 + ((ih1 & 1) ^ 1);
            smem[ri(68 + slot, c)] = smem[ri(srcrow, c)];
        }
        asm volatile("s_waitcnt lgkmcnt(0)" ::: "memory");

        int cur_lo = 64, cur_hi = 66;
#pragma unroll 1
        for (int wl = 1; wl <= 10; ++wl) {
            int il = lo >> wl, ih = hi >> wl;
            int ilc = lo >> (wl - 1), ihc = hi >> (wl - 1);
            auto child_row = [&](int c) -> int {
                if (c == ilc) return cur_lo;
                if (c == ihc) return cur_hi;
                int clow = c << (wl - 1);
                int chigh = clow + (1 << (wl - 1)) - 1;
                if (lo <= clow && hi >= chigh)
                    return 64 + (wl - 1) * 4 + ((c == (ilc ^ 1)) ? 1 : 3);
                return 139;  // raw inf
            };
            int np = (wl <= 4) ? (16 >> wl) : 0;
            int rowL, rowR, dst;
            bool wm = true, istree = false;
            if (pl < np)       { rowL = 2 * pl; rowR = 2 * pl + 1; dst = pl; istree = true; }
            else if (wl == 1 && pl >= 8 && pl < 12) {
                int s2 = pl - 8; rowL = 111 + 2 * s2; rowR = 112 + 2 * s2; dst = 72 + s2;
            }
            else if (pl == 14) { rowL = child_row(2 * il); rowR = child_row(2 * il + 1); dst = 109; }
            else if (pl == 15) { rowL = child_row(2 * ih); rowR = child_row(2 * ih + 1); dst = 110; }
            else               { rowL = 139; rowR = 139; dst = 111; wm = false; }
            int rLa[1] = {rowL}, rRa[1] = {rowR};
            U4H8 q1[1][2];
            combine_lds<1, true>(smem, rLa, rRa, wfd, pl, g, q1);
            if (wm) { smem[ri(dst, g)] = q1[0][0].u; smem[ri(dst, g + 4)] = q1[0][1].u; }
            if (istree) capl(wl + 6, pl, q1[0]);
            int low = il << wl, high = low + (1 << wl) - 1;
            cur_lo = (lo <= low && hi >= high) ? (64 + wl * 4) : 109;
            int low2 = ih << wl, high2 = low2 + (1 << wl) - 1;
            cur_hi = (lo <= low2 && hi >= high2) ? (64 + wl * 4 + 2) : 110;
            asm volatile("s_waitcnt lgkmcnt(0)" ::: "memory");
        }
        float rvv = (float)((_Float16*)smem)[ri(cur_lo, lane >> 3) * 8 + (lane & 7)];
#pragma unroll
        for (int c = 0; c < NCLS; ++c) {
            float sres = wave_sum(rvv * lin_w[c * 64 + lane]);
            if (lane == 0) out[b * NCLS + c] = sres;
        }
        asm volatile("s_waitcnt lgkmcnt(0)" ::: "memory");
    }
}

// ======================= fallback kernels (R12, proven) =======================
__global__ void __launch_bounds__(64, 4) fold_kernel(
    const int* __restrict__ x, uint4* __restrict__ ws4) {
    __shared__ uint4 trs[(64 + 12) * 9];
    const int lane = threadIdx.x;
    const int pl = lane & 15, g = lane >> 4;
    const int b = blockIdx.x >> 3, s = blockIdx.x & 7;
    half8 wfd[2][4];
    load_wfd(ws4, wfd, lane);
    {
        int r = lane >> 3, c = lane & 7;
        trs[ri(64 + r, c)] = ws4[512 + lane];
        int idx = lane + 64;
        if (idx < 96) trs[ri(64 + (idx >> 3), idx & 7)] = ws4[512 + idx];
    }
    const int2* x2 = (const int2*)x;
    int2 c00 = x2[b * 512 + s * 64 + pl];
    int2 c01 = x2[b * 512 + s * 64 + 16 + pl];
    int2 c10 = x2[b * 512 + s * 64 + 32 + pl];
    int2 c11 = x2[b * 512 + s * 64 + 48 + pl];
    asm volatile("s_waitcnt lgkmcnt(0) vmcnt(0)" ::: "memory");
    U4H8 q[2][2];
    {
        int rL[2] = {64 + c00.x, 64 + c01.x}, rR[2] = {64 + c00.y, 64 + c01.y};
        combine_lds<2, false>(trs, rL, rR, wfd, pl, g, q);
        trs[ri(pl, g)] = q[0][0].u;      trs[ri(pl, g + 4)] = q[0][1].u;
        trs[ri(16 + pl, g)] = q[1][0].u; trs[ri(16 + pl, g + 4)] = q[1][1].u;
    }
    {
        int rL[2] = {64 + c10.x, 64 + c11.x}, rR[2] = {64 + c10.y, 64 + c11.y};
        combine_lds<2, false>(trs, rL, rR, wfd, pl, g, q);
        trs[ri(32 + pl, g)] = q[0][0].u; trs[ri(32 + pl, g + 4)] = q[0][1].u;
        trs[ri(48 + pl, g)] = q[1][0].u; trs[ri(48 + pl, g + 4)] = q[1][1].u;
    }
    asm volatile("s_waitcnt lgkmcnt(0)" ::: "memory");
    {
        int rL[2] = {2 * pl, 32 + 2 * pl}, rR[2] = {2 * pl + 1, 33 + 2 * pl};
        combine_lds<2, false>(trs, rL, rR, wfd, pl, g, q);
        trs[ri(pl, g)] = q[0][0].u;      trs[ri(pl, g + 4)] = q[0][1].u;
        trs[ri(16 + pl, g)] = q[1][0].u; trs[ri(16 + pl, g + 4)] = q[1][1].u;
    }
    asm volatile("s_waitcnt lgkmcnt(0)" ::: "memory");
    {
        int rL[1] = {2 * pl}, rR[1] = {2 * pl + 1};
        U4H8 q1[1][2];
        combine_lds<1, false>(trs, rL, rR, wfd, pl, g, q1);
        long gr = 1024 + (long)(b * 128 + s * 16 + pl) * 8;
        ws4[gr + g] = q1[0][0].u;
        ws4[gr + 4 + g] = q1[0][1].u;
    }
}

__global__ void __launch_bounds__(64, 2) topwalk_kernel(
    const int* __restrict__ x, const int* __restrict__ qlo_p,
    const int* __restrict__ qhi_p, const float* __restrict__ lin_w,
    float* __restrict__ out, const uint4* __restrict__ ws4) {
    __shared__ uint4 scr[196 * 9];
    const int lane = threadIdx.x;
    const int pl = lane & 15, g = lane >> 4;
    const int b = blockIdx.x;
    const int lo = qlo_p[b], hi = qhi_p[b];
    half8 wfd[2][4];
    load_wfd(ws4, wfd, lane);
    {
        int r = lane >> 3, c = lane & 7;
        scr[ri(184 + r, c)] = ws4[512 + lane];
        int idx = lane + 64;
        if (idx < 96) scr[ri(184 + (idx >> 3), idx & 7)] = ws4[512 + idx];
    }
#pragma unroll
    for (int i = 0; i < 16; ++i) {
        int idx = i * 64 + lane;
        scr[ri(idx >> 3, idx & 7)] = ws4[1024 + (long)b * 1024 + idx];
    }
    asm volatile("s_waitcnt lgkmcnt(0) vmcnt(0)" ::: "memory");
    if (lane < 32) {
        int slot = lane >> 3, c = lane & 7;
        int il3 = lo >> 3, ih3 = hi >> 3;
        int t3 = (slot == 0) ? il3 : (slot == 1) ? (il3 ^ 1) : (slot == 2) ? ih3 : (ih3 ^ 1);
        scr[ri(140 + slot, c)] = scr[ri(t3, c)];
        int t0 = (slot == 0) ? lo : (slot == 1) ? (lo ^ 1) : (slot == 2) ? hi : (hi ^ 1);
        int cls = x[b * 1024 + t0];
        scr[ri(128 + slot, c)] = scr[ri(184 + cls, c)];
    }
    asm volatile("s_waitcnt lgkmcnt(0) vmcnt(0)" ::: "memory");
    auto capl = [&](int lev, int node, const U4H8 (&qq)[2]) {
        int il = lo >> lev, ih = hi >> lev, cnt = 1024 >> lev;
        int svb = 128 + lev * 4;
        if (node == il) { scr[ri(svb, g)] = qq[0].u; scr[ri(svb, g + 4)] = qq[1].u; }
        if (((il ^ 1) < cnt) && node == (il ^ 1)) { scr[ri(svb + 1, g)] = qq[0].u; scr[ri(svb + 1, g + 4)] = qq[1].u; }
        if (node == ih) { scr[ri(svb + 2, g)] = qq[0].u; scr[ri(svb + 2, g + 4)] = qq[1].u; }
        if (((ih ^ 1) < cnt) && node == (ih ^ 1)) { scr[ri(svb + 3, g)] = qq[0].u; scr[ri(svb + 3, g + 4)] = qq[1].u; }
    };
    U4H8 q[2][2];
    {
        int rL[2] = {2 * pl, 32 + 2 * pl}, rR[2] = {2 * pl + 1, 33 + 2 * pl};
        combine_lds<2, false>(scr, rL, rR, wfd, pl, g, q);
        scr[ri(pl, g)] = q[0][0].u;      scr[ri(pl, g + 4)] = q[0][1].u;
        scr[ri(16 + pl, g)] = q[1][0].u; scr[ri(16 + pl, g + 4)] = q[1][1].u;
        capl(4, pl, q[0]); capl(4, 16 + pl, q[1]);
    }
    {
        int rL[2] = {64 + 2 * pl, 96 + 2 * pl}, rR[2] = {65 + 2 * pl, 97 + 2 * pl};
        combine_lds<2, false>(scr, rL, rR, wfd, pl, g, q);
        scr[ri(32 + pl, g)] = q[0][0].u; scr[ri(32 + pl, g + 4)] = q[0][1].u;
        scr[ri(48 + pl, g)] = q[1][0].u; scr[ri(48 + pl, g + 4)] = q[1][1].u;
        capl(4, 32 + pl, q[0]); capl(4, 48 + pl, q[1]);
    }
    asm volatile("s_waitcnt lgkmcnt(0)" ::: "memory");
    {
        int rL[2] = {2 * pl, 32 + 2 * pl}, rR[2] = {2 * pl + 1, 33 + 2 * pl};
        combine_lds<2, false>(scr, rL, rR, wfd, pl, g, q);
        scr[ri(pl, g)] = q[0][0].u;      scr[ri(pl, g + 4)] = q[0][1].u;
        scr[ri(16 + pl, g)] = q[1][0].u; scr[ri(16 + pl, g + 4)] = q[1][1].u;
        capl(5, pl, q[0]); capl(5, 16 + pl, q[1]);
    }
    asm volatile("s_waitcnt lgkmcnt(0)" ::: "memory");
    const int il1 = lo >> 1, ih1 = hi >> 1, il2 = lo >> 2, ih2 = hi >> 2;
    {
        const int2* x2 = (const int2*)x;
        bool aact = pl < 8;
        int nn1 = 0;
        if (aact) {
            int base2 = (pl < 4) ? ((pl < 2) ? il2 : (il2 ^ 1))
                                 : ((pl < 6) ? ih2 : (ih2 ^ 1));
            nn1 = 2 * base2 + (pl & 1);
        }
        int2 lv = aact ? x2[b * 512 + nn1] : make_int2(0, 0);
        int rL[2] = {2 * pl, aact ? 184 + lv.x : 184};
        int rR[2] = {2 * pl + 1, aact ? 184 + lv.y : 184};
        combine_lds<2, false>(scr, rL, rR, wfd, pl, g, q);
        asm volatile("s_waitcnt lgkmcnt(0)" ::: "memory");
        scr[ri(pl, g)] = q[0][0].u; scr[ri(pl, g + 4)] = q[0][1].u;
        capl(6, pl, q[0]);
        if (aact) { scr[ri(175 + pl, g)] = q[1][0].u; scr[ri(175 + pl, g + 4)] = q[1][1].u; }
    }
    asm volatile("s_waitcnt lgkmcnt(0)" ::: "memory");
    if (lane < 32) {
        int slot = lane >> 3, c = lane & 7;
        int srcrow = (slot == 0) ? 175 + (il1 & 1)
                   : (slot == 1) ? 175 + ((il1 & 1) ^ 1)
                   : (slot == 2) ? 179 + (ih1 & 1)
                                 : 179 + ((ih1 & 1) ^ 1);
        scr[ri(132 + slot, c)] = scr[ri(srcrow, c)];
    }
    asm volatile("s_waitcnt lgkmcnt(0)" ::: "memory");
    int cur_lo = 128, cur_hi = 130;
#pragma unroll 1
    for (int wl = 1; wl <= 10; ++wl) {
        int il = lo >> wl, ih = hi >> wl;
        int ilc = lo >> (wl - 1), ihc = hi >> (wl - 1);
        auto child_row = [&](int c) -> int {
            if (c == ilc) return cur_lo;
            if (c == ihc) return cur_hi;
            int clow = c << (wl - 1);
            int chigh = clow + (1 << (wl - 1)) - 1;
            if (lo <= clow && hi >= chigh)
                return 128 + (wl - 1) * 4 + ((c == (ilc ^ 1)) ? 1 : 3);
            return 195;
        };
        int np = (wl <= 4) ? (16 >> wl) : 0;
        int rowL, rowR, dst;
        bool wm = true, istree = false;
        if (pl < np)       { rowL = 2 * pl; rowR = 2 * pl + 1; dst = pl; istree = true; }
        else if (wl == 1 && pl >= 8 && pl < 12) {
            int s2 = pl - 8; rowL = 175 + 2 * s2; rowR = 176 + 2 * s2; dst = 136 + s2;
        }
        else if (pl == 14) { rowL = child_row(2 * il); rowR = child_row(2 * il + 1); dst = 173; }
        else if (pl == 15) { rowL = child_row(2 * ih); rowR = child_row(2 * ih + 1); dst = 174; }
        else               { rowL = 195; rowR = 195; dst = 175; wm = false; }
        int rLa[1] = {rowL}, rRa[1] = {rowR};
        U4H8 q1[1][2];
        combine_lds<1, true>(scr, rLa, rRa, wfd, pl, g, q1);
        if (wm) { scr[ri(dst, g)] = q1[0][0].u; scr[ri(dst, g + 4)] = q1[0][1].u; }
        if (istree) capl(wl + 6, pl, q1[0]);
        int low = il << wl, high = low + (1 << wl) - 1;
        cur_lo = (lo <= low && hi >= high) ? (128 + wl * 4) : 173;
        int low2 = ih << wl, high2 = low2 + (1 << wl) - 1;
        cur_hi = (lo <= low2 && hi >= high2) ? (128 + wl * 4 + 2) : 174;
        asm volatile("s_waitcnt lgkmcnt(0)" ::: "memory");
    }
    float rvv = (float)((_Float16*)scr)[ri(cur_lo, lane >> 3) * 8 + (lane & 7)];
#pragma unroll
    for (int c = 0; c < NCLS; ++c) {
        float s = wave_sum(rvv * lin_w[c * 64 + lane]);
        if (lane == 0) out[b * NCLS + c] = s;
    }
}

extern "C" void kernel_launch(void* const* d_in, const int* in_sizes, int n_in,
                              void* d_out, int out_size, void* d_ws, size_t ws_size,
                              hipStream_t stream) {
    const int* x = (const int*)d_in[0];
    const int* qlo = (const int*)d_in[1];
    const int* qhi = (const int*)d_in[2];
    const float* emb = (const float*)d_in[3];
    const float* rule_w = (const float*)d_in[4];
    const float* lin_w = (const float*)d_in[5];
    float* out = (float*)d_out;
    uint4* ws4 = (uint4*)d_ws;  // 1024 + 1024*128*8 uint4 ~= 16.8 MB

    setup_kernel<<<8, 256, 0, stream>>>(emb, rule_w, ws4);

    int coop = 0;
    hipDeviceGetAttribute(&coop, hipDeviceAttributeCooperativeLaunch, 0);
    int nb = 0;
    hipOccupancyMaxActiveBlocksPerMultiprocessor(&nb, (const void*)fused_kernel, 128, 0);
    if (coop && nb > 0) {
        int grid = nb * 256;
        if (grid > 2048) grid = 2048;
        void* kargs[] = {(void*)&x, (void*)&qlo, (void*)&qhi,
                         (void*)&lin_w, (void*)&out, (void*)&ws4};
        hipLaunchCooperativeKernel((const void*)fused_kernel, dim3(grid), dim3(128),
                                   kargs, 0, stream);
    } else {
        fold_kernel<<<8192, 64, 0, stream>>>(x, ws4);
        topwalk_kernel<<<1024, 64, 0, stream>>>(x, qlo, qhi, lin_w, out, ws4);
    }
}

// Round 14
// 53.225 us; speedup vs baseline: 4.5527x; 4.5527x over previous
//
#include <hip/hip_runtime.h>

#define NCLS 10

typedef _Float16 half8 __attribute__((ext_vector_type(8)));
typedef _Float16 h2 __attribute__((ext_vector_type(2)));
typedef __fp16 fp16x2 __attribute__((ext_vector_type(2)));
typedef float f32x4 __attribute__((ext_vector_type(4)));
typedef unsigned int u32;

#define MFMA(A, B, C) __builtin_amdgcn_mfma_f32_16x16x32_f16(A, B, C, 0, 0, 0)

union U4H8 { uint4 u; half8 h; h2 p[4]; u32 w[4]; };
union U2H4 { uint2 u; h2 p[2]; };
union HCVT { fp16x2 f; h2 h; u32 w; };

// node rows = 9 uint4 (8 data + 1 pad): linear addressing at ~4-way max alias
__device__ __forceinline__ int ri(int row, int c) { return row * 9 + c; }
__device__ __forceinline__ h2 pk2(float a, float b) { HCVT u; u.f = __builtin_amdgcn_cvt_pkrtz(a, b); return u.h; }
__device__ __forceinline__ u32 packh2(float a, float b) { HCVT u; u.f = __builtin_amdgcn_cvt_pkrtz(a, b); return u.w; }
__device__ __forceinline__ float fdot2f(h2 a, h2 b, float c) { return __builtin_amdgcn_fdot2(a, b, c, false); }
__device__ __forceinline__ float rsqf(float x) {
#if __has_builtin(__builtin_amdgcn_rsqf)
    return __builtin_amdgcn_rsqf(x);
#else
    return __builtin_amdgcn_rcpf(__builtin_amdgcn_sqrtf(x));
#endif
}
__device__ __forceinline__ float wave_sum(float v) {
#pragma unroll
    for (int m = 1; m < 64; m <<= 1) v += __shfl_xor(v, m, 64);
    return v;
}
__device__ __forceinline__ float red4(float v) {
    v += __shfl_xor(v, 16, 64);
    v += __shfl_xor(v, 32, 64);
    return v;
}

// N-stream 16-pair combine. Wd = W1-W0 single matvec. EXACT: true norms.
template <int N, bool EXACT>
__device__ __forceinline__ void combine_core(const U4H8 (&La)[N][2], const U4H8 (&Ra)[N][2],
                                             const U2H4 (&rv)[N][4], const half8 (&wfd)[2][4],
                                             U4H8 (&q)[N][2]) {
    float sd[N], lr[N], ll[N], rr[N];
#pragma unroll
    for (int n = 0; n < N; ++n) { sd[n] = 0.f; lr[n] = 0.f; ll[n] = 0.f; rr[n] = 0.f; }
#pragma unroll
    for (int mb = 0; mb < 4; ++mb)
#pragma unroll
        for (int n = 0; n < N; ++n) {
            f32x4 t = {0.f, 0.f, 0.f, 0.f};
#pragma unroll
            for (int kb = 0; kb < 2; ++kb) t = MFMA(wfd[kb][mb], La[n][kb].h, t);
            sd[n] = fdot2f(pk2(t[0], t[1]), rv[n][mb].p[0],
                           fdot2f(pk2(t[2], t[3]), rv[n][mb].p[1], sd[n]));
        }
#pragma unroll
    for (int n = 0; n < N; ++n)
#pragma unroll
        for (int kb = 0; kb < 2; ++kb)
#pragma unroll
            for (int i = 0; i < 4; ++i) {
                h2 l2 = La[n][kb].p[i], r2 = Ra[n][kb].p[i];
                lr[n] = fdot2f(l2, r2, lr[n]);
                if (EXACT) { ll[n] = fdot2f(l2, l2, ll[n]); rr[n] = fdot2f(r2, r2, rr[n]); }
            }
#pragma unroll
    for (int n = 0; n < N; ++n) {
        sd[n] = red4(sd[n]); lr[n] = red4(lr[n]);
        if (EXACT) { ll[n] = red4(ll[n]); rr[n] = red4(rr[n]); }
    }
#pragma unroll
    for (int n = 0; n < N; ++n) {
        float u = __expf(sd[n]);
        float a0 = __builtin_amdgcn_rcpf(1.f + u), a1 = 1.f - a0;
        float ms = EXACT ? (a0 * a0 * ll[n] + 2.f * a0 * a1 * lr[n] + a1 * a1 * rr[n]) * (1.f / 64.f)
                         : a0 * a0 + a1 * a1 + a0 * a1 * lr[n] * (2.f / 64.f);
        float sc = rsqf(ms + 1e-6f);
        h2 c0 = pk2(a0 * sc, a0 * sc), c1 = pk2(a1 * sc, a1 * sc);
#pragma unroll
        for (int kb = 0; kb < 2; ++kb)
#pragma unroll
            for (int i = 0; i < 4; ++i)
                q[n][kb].p[i] = c0 * La[n][kb].p[i] + c1 * Ra[n][kb].p[i];
    }
}

__device__ __forceinline__ void load_bfrag(const uint4* src, int row, int g, U4H8 (&A)[2]) {
    A[0].u = src[ri(row, g)];
    A[1].u = src[ri(row, g + 4)];
}
__device__ __forceinline__ void load_rv4(const uint4* src, int row, int g, U2H4 (&rv)[4]) {
    const uint2* s2 = (const uint2*)src;
#pragma unroll
    for (int mb = 0; mb < 4; ++mb) rv[mb].u = s2[ri(row, 2 * mb + (g >> 1)) * 2 + (g & 1)];
}
template <int N, bool EXACT>
__device__ __forceinline__ void combine_lds(const uint4* src, const int (&rowL)[N],
                                            const int (&rowR)[N], const half8 (&wfd)[2][4],
                                            int pl, int g, U4H8 (&q)[N][2]) {
    U4H8 La[N][2], Ra[N][2];
    U2H4 rv[N][4];
#pragma unroll
    for (int n = 0; n < N; ++n) {
        load_bfrag(src, rowL[n], g, La[n]);
        load_bfrag(src, rowR[n], g, Ra[n]);
        load_rv4(src, rowR[n], g, rv[n]);
    }
    combine_core<N, EXACT>(La, Ra, rv, wfd, q);
}

// ws layout (uint4): [0..511] Wd frags; [512..607] ermsh rows 0-11 (row 11 = RAW inf);
// batch b lev3 nodes at 1024+(b*128+r)*8 (LINEAR 8-chunk rows).
__device__ __forceinline__ void load_wfd(const uint4* ws4, half8 (&wfd)[2][4], int lane) {
#pragma unroll
    for (int fm = 0; fm < 8; ++fm) {
        U4H8 t;
        t.u = ws4[fm * 64 + lane];
        wfd[fm >> 2][fm & 3] = t.h;
    }
}

// ======================= kernel 0: setup =======================
__global__ void setup_kernel(const float* __restrict__ emb,
                             const float* __restrict__ rule_w, uint4* __restrict__ ws4) {
    int tid = threadIdx.x;
    int idx = blockIdx.x * 256 + tid;  // 0..2047
    {
        int e2 = idx & 3, lane = (idx >> 2) & 63, fm = idx >> 8;
        int kb = fm >> 2, mb = fm & 3, pl = lane & 15, g = lane >> 4;
        int i0 = 32 * kb + 8 * g + 2 * e2, j = 16 * mb + pl;
        float d0 = rule_w[4096 + i0 * 64 + j] - rule_w[i0 * 64 + j];
        float d1 = rule_w[4096 + (i0 + 1) * 64 + j] - rule_w[(i0 + 1) * 64 + j];
        ((u32*)ws4)[idx] = packh2(d0, d1);
    }
    if (blockIdx.x == 0 && tid < 64) {
        int lane = tid;
        u32* eg = (u32*)(ws4 + 512);
        for (int r = 0; r < 11; ++r) {
            float e = emb[r * 64 + lane];
            float ms = wave_sum(e * e) * (1.f / 64.f);
            float v = e * __builtin_amdgcn_rcpf(__builtin_amdgcn_sqrtf(ms + 1e-6f) + 1e-6f);
            u32 w = packh2(v, __shfl_xor(v, 1, 64));
            if ((lane & 1) == 0) eg[r * 32 + (lane >> 1)] = w;
        }
        float e = emb[640 + lane];  // raw inf token -> row 11
        u32 w = packh2(e, __shfl_xor(e, 1, 64));
        if ((lane & 1) == 0) eg[11 * 32 + (lane >> 1)] = w;
    }
}

// ======================= kernel 1: fold lev1-3 (1 wave = 1 subtree) ==========
// Single-wave-private LDS: DS ops execute in issue order within a wave, so NO
// explicit lgkmcnt drains between levels — compiler inserts minimal waits.
__global__ void __launch_bounds__(64, 4) fold_kernel(
    const int* __restrict__ x, uint4* __restrict__ ws4) {
    __shared__ uint4 trs[(64 + 12) * 9];  // 10.9 KB: rows 0-63 tree, 64-75 ermsh
    const int lane = threadIdx.x;
    const int pl = lane & 15, g = lane >> 4;
    const int b = blockIdx.x >> 3, s = blockIdx.x & 7;

    half8 wfd[2][4];
    load_wfd(ws4, wfd, lane);
    {
        int r = lane >> 3, c = lane & 7;
        trs[ri(64 + r, c)] = ws4[512 + lane];
        int idx = lane + 64;
        if (idx < 96) trs[ri(64 + (idx >> 3), idx & 7)] = ws4[512 + idx];
    }
    const int2* x2 = (const int2*)x;
    int2 c00 = x2[b * 512 + s * 64 + pl];
    int2 c01 = x2[b * 512 + s * 64 + 16 + pl];
    int2 c10 = x2[b * 512 + s * 64 + 32 + pl];
    int2 c11 = x2[b * 512 + s * 64 + 48 + pl];

    U4H8 q[2][2];
    // lev1 pairs 0-31 -> rows 0-31
    {
        int rL[2] = {64 + c00.x, 64 + c01.x}, rR[2] = {64 + c00.y, 64 + c01.y};
        combine_lds<2, false>(trs, rL, rR, wfd, pl, g, q);
        trs[ri(pl, g)] = q[0][0].u;      trs[ri(pl, g + 4)] = q[0][1].u;
        trs[ri(16 + pl, g)] = q[1][0].u; trs[ri(16 + pl, g + 4)] = q[1][1].u;
    }
    // lev1 pairs 32-63 -> rows 32-63
    {
        int rL[2] = {64 + c10.x, 64 + c11.x}, rR[2] = {64 + c10.y, 64 + c11.y};
        combine_lds<2, false>(trs, rL, rR, wfd, pl, g, q);
        trs[ri(32 + pl, g)] = q[0][0].u; trs[ri(32 + pl, g + 4)] = q[0][1].u;
        trs[ri(48 + pl, g)] = q[1][0].u; trs[ri(48 + pl, g + 4)] = q[1][1].u;
    }
    // lev2 (32 pairs) -> rows 0-31
    {
        int rL[2] = {2 * pl, 32 + 2 * pl}, rR[2] = {2 * pl + 1, 33 + 2 * pl};
        combine_lds<2, false>(trs, rL, rR, wfd, pl, g, q);
        trs[ri(pl, g)] = q[0][0].u;      trs[ri(pl, g + 4)] = q[0][1].u;
        trs[ri(16 + pl, g)] = q[1][0].u; trs[ri(16 + pl, g + 4)] = q[1][1].u;
    }
    // lev3 (16 pairs) -> global lev3 rows (LINEAR 8-chunk)
    {
        int rL[1] = {2 * pl}, rR[1] = {2 * pl + 1};
        U4H8 q1[1][2];
        combine_lds<1, false>(trs, rL, rR, wfd, pl, g, q1);
        long gr = 1024 + (long)(b * 128 + s * 16 + pl) * 8;
        ws4[gr + g] = q1[0][0].u;
        ws4[gr + 4 + g] = q1[0][1].u;
    }
}

// ======================= kernel 2: top fold + sv rebuild + query walk ========
// Single-wave block: no explicit LDS drains needed (in-order DS per wave).
// scr rows: 0-127 tree (lev3 in, folded in place), 128+l*4+s sv (128-171),
// 173 res_lo, 174 res_hi, 175-182 A-ride lev1 nodes, 184-195 ermsh (195 raw inf)
__global__ void __launch_bounds__(64, 2) topwalk_kernel(
    const int* __restrict__ x, const int* __restrict__ qlo_p,
    const int* __restrict__ qhi_p, const float* __restrict__ lin_w,
    float* __restrict__ out, const uint4* __restrict__ ws4) {
    __shared__ uint4 scr[196 * 9];  // 28.2 KB
    const int lane = threadIdx.x;
    const int pl = lane & 15, g = lane >> 4;
    const int b = blockIdx.x;
    const int lo = qlo_p[b], hi = qhi_p[b];

    half8 wfd[2][4];
    load_wfd(ws4, wfd, lane);
    {
        int r = lane >> 3, c = lane & 7;
        scr[ri(184 + r, c)] = ws4[512 + lane];
        int idx = lane + 64;
        if (idx < 96) scr[ri(184 + (idx >> 3), idx & 7)] = ws4[512 + idx];
    }
#pragma unroll
    for (int i = 0; i < 16; ++i) {
        int idx = i * 64 + lane;
        scr[ri(idx >> 3, idx & 7)] = ws4[1024 + (long)b * 1024 + idx];
    }
    // sv lev3 (from tree rows) + sv lev0 (ermsh by class)
    if (lane < 32) {
        int slot = lane >> 3, c = lane & 7;
        int il3 = lo >> 3, ih3 = hi >> 3;
        int t3 = (slot == 0) ? il3 : (slot == 1) ? (il3 ^ 1) : (slot == 2) ? ih3 : (ih3 ^ 1);
        scr[ri(140 + slot, c)] = scr[ri(t3, c)];
        int t0 = (slot == 0) ? lo : (slot == 1) ? (lo ^ 1) : (slot == 2) ? hi : (hi ^ 1);
        int cls = x[b * 1024 + t0];
        scr[ri(128 + slot, c)] = scr[ri(184 + cls, c)];
    }

    auto capl = [&](int lev, int node, const U4H8 (&qq)[2]) {
        int il = lo >> lev, ih = hi >> lev, cnt = 1024 >> lev;
        int svb = 128 + lev * 4;
        if (node == il) { scr[ri(svb, g)] = qq[0].u; scr[ri(svb, g + 4)] = qq[1].u; }
        if (((il ^ 1) < cnt) && node == (il ^ 1)) { scr[ri(svb + 1, g)] = qq[0].u; scr[ri(svb + 1, g + 4)] = qq[1].u; }
        if (node == ih) { scr[ri(svb + 2, g)] = qq[0].u; scr[ri(svb + 2, g + 4)] = qq[1].u; }
        if (((ih ^ 1) < cnt) && node == (ih ^ 1)) { scr[ri(svb + 3, g)] = qq[0].u; scr[ri(svb + 3, g + 4)] = qq[1].u; }
    };

    U4H8 q[2][2];
    // lev4 (64 pairs): 2 independent calls <2>
    {
        int rL[2] = {2 * pl, 32 + 2 * pl}, rR[2] = {2 * pl + 1, 33 + 2 * pl};
        combine_lds<2, false>(scr, rL, rR, wfd, pl, g, q);
        scr[ri(pl, g)] = q[0][0].u;      scr[ri(pl, g + 4)] = q[0][1].u;
        scr[ri(16 + pl, g)] = q[1][0].u; scr[ri(16 + pl, g + 4)] = q[1][1].u;
        capl(4, pl, q[0]); capl(4, 16 + pl, q[1]);
    }
    {
        int rL[2] = {64 + 2 * pl, 96 + 2 * pl}, rR[2] = {65 + 2 * pl, 97 + 2 * pl};
        combine_lds<2, false>(scr, rL, rR, wfd, pl, g, q);
        scr[ri(32 + pl, g)] = q[0][0].u; scr[ri(32 + pl, g + 4)] = q[0][1].u;
        scr[ri(48 + pl, g)] = q[1][0].u; scr[ri(48 + pl, g + 4)] = q[1][1].u;
        capl(4, 32 + pl, q[0]); capl(4, 48 + pl, q[1]);
    }
    // lev5 (32 pairs)
    {
        int rL[2] = {2 * pl, 32 + 2 * pl}, rR[2] = {2 * pl + 1, 33 + 2 * pl};
        combine_lds<2, false>(scr, rL, rR, wfd, pl, g, q);
        scr[ri(pl, g)] = q[0][0].u;      scr[ri(pl, g + 4)] = q[0][1].u;
        scr[ri(16 + pl, g)] = q[1][0].u; scr[ri(16 + pl, g + 4)] = q[1][1].u;
        capl(5, pl, q[0]); capl(5, 16 + pl, q[1]);
    }
    // lev6 (16 pairs) + A-ride (8 lev1 sv-support nodes from leaves)
    const int il1 = lo >> 1, ih1 = hi >> 1, il2 = lo >> 2, ih2 = hi >> 2;
    {
        const int2* x2 = (const int2*)x;
        bool aact = pl < 8;
        int nn1 = 0;
        if (aact) {
            int base2 = (pl < 4) ? ((pl < 2) ? il2 : (il2 ^ 1))
                                 : ((pl < 6) ? ih2 : (ih2 ^ 1));
            nn1 = 2 * base2 + (pl & 1);
        }
        int2 lv = aact ? x2[b * 512 + nn1] : make_int2(0, 0);
        int rL[2] = {2 * pl, aact ? 184 + lv.x : 184};
        int rR[2] = {2 * pl + 1, aact ? 184 + lv.y : 184};
        combine_lds<2, false>(scr, rL, rR, wfd, pl, g, q);
        scr[ri(pl, g)] = q[0][0].u; scr[ri(pl, g + 4)] = q[0][1].u;
        capl(6, pl, q[0]);
        if (aact) { scr[ri(175 + pl, g)] = q[1][0].u; scr[ri(175 + pl, g + 4)] = q[1][1].u; }
    }
    // sv lev1 copies from A-ride rows
    if (lane < 32) {
        int slot = lane >> 3, c = lane & 7;
        int srcrow = (slot == 0) ? 175 + (il1 & 1)
                   : (slot == 1) ? 175 + ((il1 & 1) ^ 1)
                   : (slot == 2) ? 179 + (ih1 & 1)
                                 : 179 + ((ih1 & 1) ^ 1);
        scr[ri(132 + slot, c)] = scr[ri(srcrow, c)];
    }

    // walk wl=1..10; tree lev wl+6 rides pl<np (wl<=4); B-ride (sv lev2) at wl=1
    int cur_lo = 128, cur_hi = 130;
#pragma unroll 1
    for (int wl = 1; wl <= 10; ++wl) {
        int il = lo >> wl, ih = hi >> wl;
        int ilc = lo >> (wl - 1), ihc = hi >> (wl - 1);
        auto child_row = [&](int c) -> int {
            if (c == ilc) return cur_lo;
            if (c == ihc) return cur_hi;
            int clow = c << (wl - 1);
            int chigh = clow + (1 << (wl - 1)) - 1;
            if (lo <= clow && hi >= chigh)
                return 128 + (wl - 1) * 4 + ((c == (ilc ^ 1)) ? 1 : 3);
            return 195;  // raw inf
        };
        int np = (wl <= 4) ? (16 >> wl) : 0;
        int rowL, rowR, dst;
        bool wm = true, istree = false;
        if (pl < np)       { rowL = 2 * pl; rowR = 2 * pl + 1; dst = pl; istree = true; }
        else if (wl == 1 && pl >= 8 && pl < 12) {
            int s2 = pl - 8; rowL = 175 + 2 * s2; rowR = 176 + 2 * s2; dst = 136 + s2;
        }
        else if (pl == 14) { rowL = child_row(2 * il); rowR = child_row(2 * il + 1); dst = 173; }
        else if (pl == 15) { rowL = child_row(2 * ih); rowR = child_row(2 * ih + 1); dst = 174; }
        else               { rowL = 195; rowR = 195; dst = 175; wm = false; }
        int rLa[1] = {rowL}, rRa[1] = {rowR};
        U4H8 q1[1][2];
        combine_lds<1, true>(scr, rLa, rRa, wfd, pl, g, q1);
        if (wm) { scr[ri(dst, g)] = q1[0][0].u; scr[ri(dst, g + 4)] = q1[0][1].u; }
        if (istree) capl(wl + 6, pl, q1[0]);
        int low = il << wl, high = low + (1 << wl) - 1;
        cur_lo = (lo <= low && hi >= high) ? (128 + wl * 4) : 173;
        int low2 = ih << wl, high2 = low2 + (1 << wl) - 1;
        cur_hi = (lo <= low2 && hi >= high2) ? (128 + wl * 4 + 2) : 174;
    }
    // final linear
    float rvv = (float)((_Float16*)scr)[ri(cur_lo, lane >> 3) * 8 + (lane & 7)];
#pragma unroll
    for (int c = 0; c < NCLS; ++c) {
        float s = wave_sum(rvv * lin_w[c * 64 + lane]);
        if (lane == 0) out[b * NCLS + c] = s;
    }
}

extern "C" void kernel_launch(void* const* d_in, const int* in_sizes, int n_in,
                              void* d_out, int out_size, void* d_ws, size_t ws_size,
                              hipStream_t stream) {
    const int* x = (const int*)d_in[0];
    const int* qlo = (const int*)d_in[1];
    const int* qhi = (const int*)d_in[2];
    const float* emb = (const float*)d_in[3];
    const float* rule_w = (const float*)d_in[4];
    const float* lin_w = (const float*)d_in[5];
    float* out = (float*)d_out;
    uint4* ws4 = (uint4*)d_ws;  // 1024 + 1024*128*8 uint4 ~= 16.8 MB
    setup_kernel<<<8, 256, 0, stream>>>(emb, rule_w, ws4);
    fold_kernel<<<8192, 64, 0, stream>>>(x, ws4);
    topwalk_kernel<<<1024, 64, 0, stream>>>(x, qlo, qhi, lin_w, out, ws4);
}